// Round 12
// baseline (83.130 us; speedup 1.0000x reference)
//
#include <hip/hip_runtime.h>

#define T_TOTAL 200000
#define NL 49
#define NP 50
#define NB 20
#define TB 32                       // timesteps per block; 200000 % 32 == 0
#define THREADS 256                 // 4 waves; each wave owns 8 timesteps (+1 overlap)
#define NBLK (T_TOTAL / TB)         // 6250
#define TPW 8                       // owned timesteps per wave

// Phase A: 27 HAND-NAMED angle loads (base + imm-offset) issued back-to-back,
// pinned by a single asm fake-use (=> one vmcnt(0) round-trip per wave, full
// MLP), then 9 register shuffle-prefix chains -> positions to LDS.
// Phase B: float4 loss/reg2/output pass. LDS ~20KB.
__global__ __launch_bounds__(THREADS, 6) void bbf_fused(
    const float* __restrict__ lines,
    const float* __restrict__ rootsx,
    const float* __restrict__ rootsy,
    const float* __restrict__ rootsz,
    const float* __restrict__ ax,
    const float* __restrict__ ay,
    const float* __restrict__ az,
    const float* __restrict__ tarx,
    const float* __restrict__ tary,
    const float* __restrict__ w,
    float* __restrict__ outx,
    float* __restrict__ outy,
    float* __restrict__ outz,
    double* __restrict__ partials)   // [NBLK][2]: loss, reg2 per block
{
    __shared__ __align__(16) float xs[(TB + 1) * NP + 8];   // +8: phase-B overshoot
    __shared__ __align__(16) float ys[(TB + 1) * NP + 8];
    __shared__ __align__(16) float zs[(TB + 1) * NP + 8];
    __shared__ double redL[THREADS / 64], redR[THREADS / 64];

    const int tid  = threadIdx.x;
    const int lane = tid & 63;
    const int wv   = tid >> 6;
    const int t0   = blockIdx.x * TB;

    const bool isNode = (lane < NP);
    const bool isLimb = (lane >= 1 && lane < NP);
    const int  li     = isLimb ? (lane - 1) : 0;    // clamped limb index

    const float Lv = isLimb ? expf(lines[li % NB]) : 0.f;   // 0 masks non-limb lanes

    // ancestor jump table (pointer jumping: 1st, 2nd, 4th ancestor; root-clamped)
    const int a1 = isLimb ? ((lane - 1) >> 1) : 0;
    const int a2 = (a1 > 0) ? ((a1 - 1) >> 1) : 0;
    const int a3 = (a2 > 0) ? ((a2 - 1) >> 1) : 0;
    const int a4 = (a3 > 0) ? ((a3 - 1) >> 1) : 0;

    // ---- Phase A1: 27 named loads, base + immediate offsets (196B * k) ----
    // wave wv covers timesteps tw..tw+8; last block's k=8 clamped to T-1.
    const int tw = t0 + wv * TPW;
    const size_t gbaseA = (size_t)tw * NL + li;
    const float* axp = ax + gbaseA;
    const float* ayp = ay + gbaseA;
    const float* azp = az + gbaseA;
    const size_t off8 = (t0 + TB < T_TOTAL) ? (size_t)(8 * NL)
                                            : (size_t)(8 * NL) - (wv == 3 ? NL : 0);
    float x0,y0,z0,x1,y1,z1,x2,y2,z2,x3,y3,z3,x4,y4,z4,x5,y5,z5,x6,y6,z6,x7,y7,z7,x8,y8,z8;
    x0 = axp[0 * NL]; y0 = ayp[0 * NL]; z0 = azp[0 * NL];
    x1 = axp[1 * NL]; y1 = ayp[1 * NL]; z1 = azp[1 * NL];
    x2 = axp[2 * NL]; y2 = ayp[2 * NL]; z2 = azp[2 * NL];
    x3 = axp[3 * NL]; y3 = ayp[3 * NL]; z3 = azp[3 * NL];
    x4 = axp[4 * NL]; y4 = ayp[4 * NL]; z4 = azp[4 * NL];
    x5 = axp[5 * NL]; y5 = ayp[5 * NL]; z5 = azp[5 * NL];
    x6 = axp[6 * NL]; y6 = ayp[6 * NL]; z6 = azp[6 * NL];
    x7 = axp[7 * NL]; y7 = ayp[7 * NL]; z7 = azp[7 * NL];
    x8 = axp[off8];   y8 = ayp[off8];   z8 = azp[off8];
    // single fake-use: all 27 must be materialized here (one vmcnt wait, full MLP)
    asm volatile("" ::
        "v"(x0),"v"(y0),"v"(z0),"v"(x1),"v"(y1),"v"(z1),"v"(x2),"v"(y2),"v"(z2),
        "v"(x3),"v"(y3),"v"(z3),"v"(x4),"v"(y4),"v"(z4),"v"(x5),"v"(y5),"v"(z5),
        "v"(x6),"v"(y6),"v"(z6),"v"(x7),"v"(y7),"v"(z7),"v"(x8),"v"(y8),"v"(z8));

    // ---- Phase A2: prefix chains -> LDS (chains 0-7 all waves; 8 = wave3 halo) ----
#define CHAIN(K, XK, YK, ZK)                                                    \
    {                                                                           \
        const int t_loc = wv * TPW + (K);                                       \
        const int t = t0 + t_loc;                                               \
        const float n = sqrtf((XK) * (XK) + (YK) * (YK) + (ZK) * (ZK)) + 1e-10f;\
        const float s = Lv / n;                                                 \
        float dx = (XK) * s, dy = (YK) * s, dz = (ZK) * s;                      \
        dx += __shfl(dx, a1); dy += __shfl(dy, a1); dz += __shfl(dz, a1);       \
        dx += __shfl(dx, a2); dy += __shfl(dy, a2); dz += __shfl(dz, a2);       \
        dx += __shfl(dx, a4); dy += __shfl(dy, a4); dz += __shfl(dz, a4);       \
        if (isNode) {                                                           \
            const int o = t_loc * NP + lane;                                    \
            xs[o] = dx + rootsx[t];                                             \
            ys[o] = dy + rootsy[t];                                             \
            zs[o] = dz + rootsz[t];                                             \
        }                                                                       \
    }
    CHAIN(0, x0, y0, z0)
    CHAIN(1, x1, y1, z1)
    CHAIN(2, x2, y2, z2)
    CHAIN(3, x3, y3, z3)
    CHAIN(4, x4, y4, z4)
    CHAIN(5, x5, y5, z5)
    CHAIN(6, x6, y6, z6)
    CHAIN(7, x7, y7, z7)
    if (wv == 3 && t0 + TB < T_TOTAL) CHAIN(8, x8, y8, z8)
#undef CHAIN
    __syncthreads();

    // ---- Phase B: float4 outputs + loss/reg2 ----
    const size_t gbase = (size_t)t0 * NP;          // blockIdx*1600 floats, 16B aligned
    const float4* tarx4 = (const float4*)(tarx + gbase);
    const float4* tary4 = (const float4*)(tary + gbase);
    const float4* w4    = (const float4*)(w + gbase);
    float4* outx4 = (float4*)(outx + gbase);
    float4* outy4 = (float4*)(outy + gbase);
    float4* outz4 = (float4*)(outz + gbase);

    float lossAcc = 0.f, regAcc = 0.f;
    for (int c = tid; c < (TB * NP) / 4; c += THREADS) {   // 400 float4 groups
        const int j = c << 2;
        const float4 X  = *(const float4*)&xs[j];
        const float4 Y  = *(const float4*)&ys[j];
        const float4 Z  = *(const float4*)&zs[j];
        outx4[c] = X;
        outy4[c] = Y;
        outz4[c] = Z;
        const float4 TX = tarx4[c];
        const float4 TY = tary4[c];
        const float4 WV = w4[c];
        // next-timestep values xs[j+50..j+53] via two aligned b128 reads
        const float4 XA = *(const float4*)&xs[j + 48];
        const float4 XB = *(const float4*)&xs[j + 52];
        const float4 YA = *(const float4*)&ys[j + 48];
        const float4 YB = *(const float4*)&ys[j + 52];
        const float4 ZA = *(const float4*)&zs[j + 48];
        const float4 ZB = *(const float4*)&zs[j + 52];
        const float xv[4] = {X.x, X.y, X.z, X.w};
        const float yv[4] = {Y.x, Y.y, Y.z, Y.w};
        const float zv[4] = {Z.x, Z.y, Z.z, Z.w};
        const float tx[4] = {TX.x, TX.y, TX.z, TX.w};
        const float ty[4] = {TY.x, TY.y, TY.z, TY.w};
        const float wvv[4] = {WV.x, WV.y, WV.z, WV.w};
        const float xn[4] = {XA.z, XA.w, XB.x, XB.y};
        const float yn[4] = {YA.z, YA.w, YB.x, YB.y};
        const float zn[4] = {ZA.z, ZA.w, ZB.x, ZB.y};
#pragma unroll
        for (int e = 0; e < 4; ++e) {
            const float dx = xv[e] - tx[e];
            const float dy = yv[e] - ty[e];
            lossAcc += wvv[e] * (dx * dx + dy * dy);
            const int t = t0 + (j + e) / NP;
            if (t < T_TOTAL - 1) {
                const float ddx = xv[e] - xn[e];
                const float ddy = yv[e] - yn[e];
                const float ddz = zv[e] - zn[e];
                regAcc += ddx * ddx + ddy * ddy + ddz * ddz;
            }
        }
    }

    // wave reduce -> cross-wave LDS -> per-block partial slot
    for (int off = 32; off > 0; off >>= 1) {
        lossAcc += __shfl_down(lossAcc, off);
        regAcc  += __shfl_down(regAcc, off);
    }
    if (lane == 0) { redL[wv] = (double)lossAcc; redR[wv] = (double)regAcc; }
    __syncthreads();
    if (tid == 0) {
        double l = 0.0, r = 0.0;
        for (int i = 0; i < THREADS / 64; ++i) { l += redL[i]; r += redR[i]; }
        partials[2 * (size_t)blockIdx.x]     = l;
        partials[2 * (size_t)blockIdx.x + 1] = r;
    }
}

__global__ __launch_bounds__(256) void bbf_finalize(
    const float* __restrict__ lines,
    const double* __restrict__ partials,
    float* __restrict__ out_total)
{
    __shared__ double rl[4], rr[4];
    const int tid = threadIdx.x;
    double l = 0.0, r = 0.0;
    for (int i = tid; i < NBLK; i += 256) {
        l += partials[2 * (size_t)i];
        r += partials[2 * (size_t)i + 1];
    }
    for (int off = 32; off > 0; off >>= 1) {
        l += __shfl_down(l, off);
        r += __shfl_down(r, off);
    }
    const int wid = tid >> 6;
    if ((tid & 63) == 0) { rl[wid] = l; rr[wid] = r; }
    __syncthreads();
    if (tid == 0) {
        double L = 0.0, R = 0.0;
        for (int i = 0; i < 4; ++i) { L += rl[i]; R += rr[i]; }
        double reg1 = 0.0;
        for (int i = 0; i < NB; ++i) reg1 += (double)expf(lines[i]);
        const double loss = L / ((double)T_TOTAL * (double)NP);
        const double reg2 = R / ((double)(T_TOTAL - 1) * (double)NP);
        *out_total = (float)(loss + 0.001 * reg1 + 0.1 * reg2);
    }
}

extern "C" void kernel_launch(void* const* d_in, const int* in_sizes, int n_in,
                              void* d_out, int out_size, void* d_ws, size_t ws_size,
                              hipStream_t stream) {
    const float* lines  = (const float*)d_in[0];
    const float* rootsx = (const float*)d_in[1];
    const float* rootsy = (const float*)d_in[2];
    const float* rootsz = (const float*)d_in[3];
    const float* ax     = (const float*)d_in[4];
    const float* ay     = (const float*)d_in[5];
    const float* az     = (const float*)d_in[6];
    const float* tarx   = (const float*)d_in[7];
    const float* tary   = (const float*)d_in[8];
    const float* w      = (const float*)d_in[9];

    float* out = (float*)d_out;
    const size_t plane = (size_t)T_TOTAL * NP;
    float* outx = out;
    float* outy = out + plane;
    float* outz = out + 2 * plane;
    float* out_total = out + 3 * plane;

    double* partials = (double*)d_ws;   // NBLK*2 doubles = 100 KB

    bbf_fused<<<NBLK, THREADS, 0, stream>>>(
        lines, rootsx, rootsy, rootsz, ax, ay, az, tarx, tary, w,
        outx, outy, outz, partials);
    bbf_finalize<<<1, 256, 0, stream>>>(lines, partials, out_total);
}

// Round 13
// 78.113 us; speedup vs baseline: 1.0642x; 1.0642x over previous
//
#include <hip/hip_runtime.h>

#define T_TOTAL 200000
#define NL 49
#define NP 50
#define NB 20
#define THREADS 256
#define WPB 4                        // waves per block
#define TPW 8                        // timesteps per wave
#define NWAVES (T_TOTAL / TPW)       // 25000
#define NBLOCKS (NWAVES / WPB)       // 6250

// Zero-barrier wave-independent kernel: each wave owns 8 timesteps end-to-end.
// 27 angle loads batched (asm-pinned, one round trip), 9 register shuffle-prefix
// chains (incl. halo chain -> reg2 needs no neighbor), loss/reg2/outputs straight
// from registers. No LDS data path, no main-path __syncthreads.
__global__ __launch_bounds__(THREADS, 6) void bbf_fused(
    const float* __restrict__ lines,
    const float* __restrict__ rootsx,
    const float* __restrict__ rootsy,
    const float* __restrict__ rootsz,
    const float* __restrict__ ax,
    const float* __restrict__ ay,
    const float* __restrict__ az,
    const float* __restrict__ tarx,
    const float* __restrict__ tary,
    const float* __restrict__ w,
    float* __restrict__ outx,
    float* __restrict__ outy,
    float* __restrict__ outz,
    double* __restrict__ partials)   // [NBLOCKS][2]
{
    __shared__ double redL[WPB], redR[WPB];

    const int tid  = threadIdx.x;
    const int lane = tid & 63;
    const int wix  = tid >> 6;
    const int gw   = blockIdx.x * WPB + wix;
    const int tw   = __builtin_amdgcn_readfirstlane(gw * TPW);
    const bool lastw = (tw + TPW) >= T_TOTAL;    // last wave: no halo pair

    const bool isNode = (lane < NP);
    const bool isLimb = (lane >= 1 && lane < NP);
    const int  li = isLimb ? (lane - 1) : 0;     // clamped limb index
    const int  lc = isNode ? lane : (NP - 1);    // clamped node index (loads)

    const float Lv = isLimb ? expf(lines[li % NB]) : 0.f;

    // ancestor jump table (pointer jumping 1,2,4; depth<=5; root-clamped)
    const int a1 = isLimb ? ((lane - 1) >> 1) : 0;
    const int a2 = (a1 > 0) ? ((a1 - 1) >> 1) : 0;
    const int a3 = (a2 > 0) ? ((a2 - 1) >> 1) : 0;
    const int a4 = (a3 > 0) ? ((a3 - 1) >> 1) : 0;

    // ---- batched angle loads: 9 timesteps x 3 comps, one round trip ----
    const float* axp = ax + (size_t)tw * NL + li;
    const float* ayp = ay + (size_t)tw * NL + li;
    const float* azp = az + (size_t)tw * NL + li;
    const size_t o8 = lastw ? (size_t)(7 * NL) : (size_t)(8 * NL);   // clamp halo row
    float ax0,ay0,az0,ax1,ay1,az1,ax2,ay2,az2,ax3,ay3,az3,ax4,ay4,az4,
          ax5,ay5,az5,ax6,ay6,az6,ax7,ay7,az7,ax8,ay8,az8;
    ax0=axp[0*NL]; ay0=ayp[0*NL]; az0=azp[0*NL];
    ax1=axp[1*NL]; ay1=ayp[1*NL]; az1=azp[1*NL];
    ax2=axp[2*NL]; ay2=ayp[2*NL]; az2=azp[2*NL];
    ax3=axp[3*NL]; ay3=ayp[3*NL]; az3=azp[3*NL];
    ax4=axp[4*NL]; ay4=ayp[4*NL]; az4=azp[4*NL];
    ax5=axp[5*NL]; ay5=ayp[5*NL]; az5=azp[5*NL];
    ax6=axp[6*NL]; ay6=ayp[6*NL]; az6=azp[6*NL];
    ax7=axp[7*NL]; ay7=ayp[7*NL]; az7=azp[7*NL];
    ax8=axp[o8];   ay8=ayp[o8];   az8=azp[o8];
    asm volatile("" ::
        "v"(ax0),"v"(ay0),"v"(az0),"v"(ax1),"v"(ay1),"v"(az1),
        "v"(ax2),"v"(ay2),"v"(az2),"v"(ax3),"v"(ay3),"v"(az3),
        "v"(ax4),"v"(ay4),"v"(az4),"v"(ax5),"v"(ay5),"v"(az5),
        "v"(ax6),"v"(ay6),"v"(az6),"v"(ax7),"v"(ay7),"v"(az7),
        "v"(ax8),"v"(ay8),"v"(az8));

    // ---- tar/w loads (issued here; compiler may sink — each use is covered
    //      by the preceding chains, so either placement is fine) ----
    const float* txp = tarx + (size_t)tw * NP + lc;
    const float* typ = tary + (size_t)tw * NP + lc;
    const float* wp  = w    + (size_t)tw * NP + lc;
    const float tx0=txp[0*NP], ty0=typ[0*NP], q0=wp[0*NP];
    const float tx1=txp[1*NP], ty1=typ[1*NP], q1=wp[1*NP];
    const float tx2=txp[2*NP], ty2=typ[2*NP], q2=wp[2*NP];
    const float tx3=txp[3*NP], ty3=typ[3*NP], q3=wp[3*NP];
    const float tx4=txp[4*NP], ty4=typ[4*NP], q4=wp[4*NP];
    const float tx5=txp[5*NP], ty5=typ[5*NP], q5=wp[5*NP];
    const float tx6=txp[6*NP], ty6=typ[6*NP], q6=wp[6*NP];
    const float tx7=txp[7*NP], ty7=typ[7*NP], q7=wp[7*NP];

    float* oxp = outx + (size_t)tw * NP + lane;
    float* oyp = outy + (size_t)tw * NP + lane;
    float* ozp = outz + (size_t)tw * NP + lane;

    float lossAcc = 0.f, regAcc = 0.f;

#define CHAIN(K, AXK, AYK, AZK)                                               \
    float X##K, Y##K, Z##K;                                                   \
    {                                                                         \
        const float n = sqrtf(AXK*AXK + AYK*AYK + AZK*AZK) + 1e-10f;          \
        const float s = Lv / n;                                               \
        float dx = AXK * s, dy = AYK * s, dz = AZK * s;                       \
        dx += __shfl(dx, a1); dy += __shfl(dy, a1); dz += __shfl(dz, a1);     \
        dx += __shfl(dx, a2); dy += __shfl(dy, a2); dz += __shfl(dz, a2);     \
        dx += __shfl(dx, a4); dy += __shfl(dy, a4); dz += __shfl(dz, a4);     \
        const int tK = min(tw + (K), T_TOTAL - 1);                            \
        X##K = dx + rootsx[tK];                                               \
        Y##K = dy + rootsy[tK];                                               \
        Z##K = dz + rootsz[tK];                                               \
    }
#define EMIT(K)                                                               \
    if (isNode) {                                                             \
        oxp[(K)*NP] = X##K; oyp[(K)*NP] = Y##K; ozp[(K)*NP] = Z##K;           \
        const float ex = X##K - tx##K, ey = Y##K - ty##K;                     \
        lossAcc += q##K * (ex * ex + ey * ey);                                \
    }
#define REG2(KP, K)                                                           \
    if (isNode) {                                                             \
        const float d1 = X##KP - X##K, d2 = Y##KP - Y##K, d3 = Z##KP - Z##K;  \
        regAcc += d1 * d1 + d2 * d2 + d3 * d3;                                \
    }

    CHAIN(0, ax0, ay0, az0) EMIT(0)
    CHAIN(1, ax1, ay1, az1) EMIT(1) REG2(0, 1)
    CHAIN(2, ax2, ay2, az2) EMIT(2) REG2(1, 2)
    CHAIN(3, ax3, ay3, az3) EMIT(3) REG2(2, 3)
    CHAIN(4, ax4, ay4, az4) EMIT(4) REG2(3, 4)
    CHAIN(5, ax5, ay5, az5) EMIT(5) REG2(4, 5)
    CHAIN(6, ax6, ay6, az6) EMIT(6) REG2(5, 6)
    CHAIN(7, ax7, ay7, az7) EMIT(7) REG2(6, 7)
    if (!lastw) {            // halo chain: pair (tw+7, tw+8) only
        CHAIN(8, ax8, ay8, az8)
        REG2(7, 8)
    }
#undef CHAIN
#undef EMIT
#undef REG2

    // wave reduce -> cross-wave LDS -> per-block partial slot
    for (int off = 32; off > 0; off >>= 1) {
        lossAcc += __shfl_down(lossAcc, off);
        regAcc  += __shfl_down(regAcc, off);
    }
    if (lane == 0) { redL[wix] = (double)lossAcc; redR[wix] = (double)regAcc; }
    __syncthreads();
    if (tid == 0) {
        double l = 0.0, r = 0.0;
        for (int i = 0; i < WPB; ++i) { l += redL[i]; r += redR[i]; }
        partials[2 * (size_t)blockIdx.x]     = l;
        partials[2 * (size_t)blockIdx.x + 1] = r;
    }
}

__global__ __launch_bounds__(1024) void bbf_finalize(
    const float* __restrict__ lines,
    const double* __restrict__ partials,
    float* __restrict__ out_total)
{
    __shared__ double rl[16], rr[16];
    const int tid = threadIdx.x;
    double l = 0.0, r = 0.0;
    for (int i = tid; i < NBLOCKS; i += 1024) {
        l += partials[2 * (size_t)i];
        r += partials[2 * (size_t)i + 1];
    }
    for (int off = 32; off > 0; off >>= 1) {
        l += __shfl_down(l, off);
        r += __shfl_down(r, off);
    }
    const int wid = tid >> 6;
    if ((tid & 63) == 0) { rl[wid] = l; rr[wid] = r; }
    __syncthreads();
    if (tid == 0) {
        double L = 0.0, R = 0.0;
        for (int i = 0; i < 16; ++i) { L += rl[i]; R += rr[i]; }
        double reg1 = 0.0;
        for (int i = 0; i < NB; ++i) reg1 += (double)expf(lines[i]);
        const double loss = L / ((double)T_TOTAL * (double)NP);
        const double reg2 = R / ((double)(T_TOTAL - 1) * (double)NP);
        *out_total = (float)(loss + 0.001 * reg1 + 0.1 * reg2);
    }
}

extern "C" void kernel_launch(void* const* d_in, const int* in_sizes, int n_in,
                              void* d_out, int out_size, void* d_ws, size_t ws_size,
                              hipStream_t stream) {
    const float* lines  = (const float*)d_in[0];
    const float* rootsx = (const float*)d_in[1];
    const float* rootsy = (const float*)d_in[2];
    const float* rootsz = (const float*)d_in[3];
    const float* ax     = (const float*)d_in[4];
    const float* ay     = (const float*)d_in[5];
    const float* az     = (const float*)d_in[6];
    const float* tarx   = (const float*)d_in[7];
    const float* tary   = (const float*)d_in[8];
    const float* w      = (const float*)d_in[9];

    float* out = (float*)d_out;
    const size_t plane = (size_t)T_TOTAL * NP;
    float* outx = out;
    float* outy = out + plane;
    float* outz = out + 2 * plane;
    float* out_total = out + 3 * plane;

    double* partials = (double*)d_ws;   // NBLOCKS*2 doubles = 100 KB; fully
                                        // rewritten every call (no memset needed)

    bbf_fused<<<NBLOCKS, THREADS, 0, stream>>>(
        lines, rootsx, rootsy, rootsz, ax, ay, az, tarx, tary, w,
        outx, outy, outz, partials);
    bbf_finalize<<<1, 1024, 0, stream>>>(lines, partials, out_total);
}